// Round 3
// baseline (1061.436 us; speedup 1.0000x reference)
//
#include <hip/hip_runtime.h>

// TiThTe: sequential 3-state thermal RC scan, B=4096 elements, T=8760 steps.
// Round 5: cut issued instructions per step (now ~75% issue-bound).
//   R4 post-mortem: 165 cyc/step, VALUBusy 74% per-active-SIMD -> issue-bound.
//   Issue inventory: ~28 VALU*2 + 3 rsq*8 + ds_reads + 64-bit store addr.
// Changes vs R4 (601 us rocprof):
//   - Drop the Newton iteration: v_rsq_f32 is <=~1 ulp on gfx950 already;
//     R4 showed absmax is insensitive at this level (1024.0 exact, thr 3891).
//   - Scale-folding: all coefficients pre-scaled by 1e-5 so y = dT*1e-5 comes
//     out of the derivative fmas directly; tame+update collapses to
//     fma(t2) -> rsq -> mul -> fma-into-state  (4 instrs/state vs 7).
//       tame(dT) = dT*1e5/sqrt(dT^2+1e10) = (y*1e5)*rsqrt(y^2+1)
//   - ext consumed in groups of 4 steps: next group's 12 floats prefetched as
//     3x ds_read_b128 (48 B, 16-aligned), a full group of latency distance.
//   - 32-bit saddr stores: out is 431 MB < 4 GiB, so index with unsigned
//     dword offset -> global_store_dword v,voff,s[base]; kills the per-step
//     64-bit pointer increment.
//   - LDS staging via float4 (8760 floats/chunk stage in 35 iters).
// One thread per element; 64 blocks x 64 threads = 64 waves on 64 CUs.
// Parallelism is hard-capped at B/64 = 64 waves (serial T-recurrence), so
// wall = T * max(issue, chain); this round targets issue (~68 cyc/step).

#define CHUNK 2920   // 8760 = 3 * 2920; 2920*3*4 B = 35,040 B LDS; 2920 % 4 == 0

__global__ __launch_bounds__(64) void tithte_kernel(
    const float* __restrict__ state0,   // (B,3)
    const float* __restrict__ params,   // (B,6) : C1,R1,C2,R2,C3,R3
    const float* __restrict__ ext,      // (T,3) : T_out, heatPower, solarGains
    const int*   __restrict__ dtp,      // scalar dt
    float*       __restrict__ out,      // (T,B,3)
    int B, int T)
{
    __shared__ float sext[CHUNK * 3 + 12];   // +12: last-group prefetch pad

    const int b = blockIdx.x * blockDim.x + threadIdx.x;

    const float dtf = (float)dtp[0];

    const float C1 = params[b * 6 + 0];
    const float R1 = params[b * 6 + 1];
    const float C2 = params[b * 6 + 2];
    const float R2 = params[b * 6 + 3];
    const float C3 = params[b * 6 + 4];
    const float R3 = params[b * 6 + 5];

    const float k1 = dtf / C1;
    const float k2 = dtf / C2;
    const float k3 = dtf / C3;

    // Coefficients pre-scaled by 1e-5 (y = dT * 1e-5). ulp-level change,
    // covered by absmax headroom (1024 observed vs 3891 threshold).
    const float S    = 1.0e-5f;
    const float a11s = (k1 / R1) * S;
    const float a12s = (k1 / R2) * S;
    const float k1s  = k1 * S;
    const float a22s = (k2 / R2) * S;
    const float k2s  = k2 * S;
    const float a31s = (k3 / R1) * S;
    const float a33s = (k3 / R3) * S;

    const float TAME = 100000.0f;

    float Tin  = state0[b * 3 + 0];
    float Th   = state0[b * 3 + 1];
    float Tenv = state0[b * 3 + 2];

    // 32-bit dword offset: max index = (8759*4096+4095)*3+2 < 2^27.
    unsigned       ofs = (unsigned)b * 3u;
    const unsigned B3  = (unsigned)B * 3u;

#define STEP(TOUT, HP, SG)                                              \
    {                                                                   \
        const float k1sg = k1s * (SG);        /* off-chain */           \
        const float k2hp = k2s * (HP);        /* off-chain */           \
        const float u = Tin - Tenv;                                     \
        const float v = Tin - Th;                                       \
        const float w = (TOUT) - Tenv;                                  \
        const float y1 = fmaf(-a12s, v, fmaf(-a11s, u, k1sg));          \
        const float y2 = fmaf(a22s, v, k2hp);                           \
        const float y3 = fmaf(a31s, u, a33s * w);                       \
        const float r1 = __builtin_amdgcn_rsqf(fmaf(y1, y1, 1.0f));     \
        const float r2 = __builtin_amdgcn_rsqf(fmaf(y2, y2, 1.0f));     \
        const float r3 = __builtin_amdgcn_rsqf(fmaf(y3, y3, 1.0f));     \
        Tin  = fmaf(y1 * TAME, r1, Tin);                                \
        Th   = fmaf(y2 * TAME, r2, Th);                                 \
        Tenv = fmaf(y3 * TAME, r3, Tenv);                               \
        out[ofs]     = Tin;                                             \
        out[ofs + 1] = Th;                                              \
        out[ofs + 2] = Tenv;                                            \
        ofs += B3;                                                      \
    }

    for (int c = 0; c < T; c += CHUNK) {
        const int n = (T - c < CHUNK) ? (T - c) : CHUNK;

        __syncthreads();   // previous chunk's LDS reads done before overwrite
        {
            const int nf = n * 3;
            const int nv = nf >> 2;                       // float4 count
            const float4* __restrict__ esrc =
                (const float4*)(ext + (size_t)c * 3);     // 16B-aligned: 48c
            float4* __restrict__ edst = (float4*)sext;
            for (int i = threadIdx.x; i < nv; i += 64)
                edst[i] = esrc[i];
            for (int i = (nv << 2) + (int)threadIdx.x; i < nf; i += 64)
                sext[i] = ext[(size_t)c * 3 + i];         // tail (unused @T=8760)
        }
        __syncthreads();

        const int ngrp = n >> 2;          // full groups of 4 (n % 4 == 0 here)

        // group-0 prologue
        float4 g0 = *(const float4*)&sext[0];
        float4 g1 = *(const float4*)&sext[4];
        float4 g2 = *(const float4*)&sext[8];

        for (int g = 0; g < ngrp; ++g) {
            const int nb = (g + 1) * 12;           // next group base (pad-safe)
            const float4 n0 = *(const float4*)&sext[nb + 0];
            const float4 n1 = *(const float4*)&sext[nb + 4];
            const float4 n2 = *(const float4*)&sext[nb + 8];

            STEP(g0.x, g0.y, g0.z)
            STEP(g0.w, g1.x, g1.y)
            STEP(g1.z, g1.w, g2.x)
            STEP(g2.y, g2.z, g2.w)

            g0 = n0; g1 = n1; g2 = n2;
        }

        // scalar tail (dead at T=8760, kept for generality)
        for (int t = ngrp << 2; t < n; ++t) {
            STEP(sext[t * 3 + 0], sext[t * 3 + 1], sext[t * 3 + 2])
        }
    }
#undef STEP
}

extern "C" void kernel_launch(void* const* d_in, const int* in_sizes, int n_in,
                              void* d_out, int out_size, void* d_ws, size_t ws_size,
                              hipStream_t stream) {
    const float* state0 = (const float*)d_in[0];
    const float* params = (const float*)d_in[1];
    const float* ext    = (const float*)d_in[2];
    const int*   dtp    = (const int*)d_in[3];
    float*       out    = (float*)d_out;

    const int B = in_sizes[0] / 3;   // 4096
    const int T = in_sizes[2] / 3;   // 8760

    const int block = 64;
    const int grid  = B / block;     // 64 blocks, one wave each
    tithte_kernel<<<grid, block, 0, stream>>>(state0, params, ext, dtp, out, B, T);
}

// Round 5
// 839.631 us; speedup vs baseline: 1.2642x; 1.2642x over previous
//
#include <hip/hip_runtime.h>

// TiThTe: sequential 3-state thermal RC scan, B=4096 elements, T=8760 steps.
// Round 6 (resubmit — R6 bench was an infra failure, container died twice;
// no counters, no signal; kernel unchanged).
//   R5 post-mortem (FAILED, 601->725 us): tame cut was sound but bundled with
//   schedule regressions — group-of-4 float4 rotation (12 movs/group) and loss
//   of unroll-6 software pipelining (clustered lgkmcnt waits each group).
//   Issue stayed ~126 cyc/step, stalls rose. Revert schedule, keep numerics.
// Structure = R4 verbatim (measured 601 us):
//   CHUNK 2190, scalar sext reads prefetched one step ahead in registers,
//   #pragma unroll 6, op-pointer increment stores.
// Cuts vs R4 (all validated passing in R5, absmax 1024.0 / thr 3891):
//   - tame: drop Newton iteration (v_rsq_f32 is <=~1ulp on gfx950) and fold
//     the 1e-5 scale into the derivative coefficients:
//       tame(dT) = (y*1e5)*rsqrt(y^2+1),  y = dT*1e-5
//     -> fma(t2), rsq, mul, fma-into-state: 3 VALU + 1 rsq per state (was 7+1).
//   - y3 refactor: a33s*Tout computed off-chain from the prefetched ext value;
//     y3 = fma(a31s, u, fma(-a33s, Tenv, c3t)) — removes the w-sub from chain.
// Per-step issue estimate: ~16 VALU*2 + 3 rsq*8 + 3 st + ds/loop ~= 96 cyc
// (R4: ~122). One thread per element; 64 blocks x 64 threads = 64 waves.
// Parallelism hard-capped at B/64 = 64 waves (serial T-recurrence).

#define CHUNK 2190   // 8760 = 4 * 2190; (2190*3+3)*4 B = 26,292 B LDS

__global__ __launch_bounds__(64) void tithte_kernel(
    const float* __restrict__ state0,   // (B,3)
    const float* __restrict__ params,   // (B,6) : C1,R1,C2,R2,C3,R3
    const float* __restrict__ ext,      // (T,3) : T_out, heatPower, solarGains
    const int*   __restrict__ dtp,      // scalar dt
    float*       __restrict__ out,      // (T,B,3)
    int B, int T)
{
    __shared__ float sext[CHUNK * 3 + 3];   // +3: harmless prefetch overread

    const int b = blockIdx.x * blockDim.x + threadIdx.x;

    const float dtf = (float)dtp[0];

    const float C1 = params[b * 6 + 0];
    const float R1 = params[b * 6 + 1];
    const float C2 = params[b * 6 + 2];
    const float R2 = params[b * 6 + 3];
    const float C3 = params[b * 6 + 4];
    const float R3 = params[b * 6 + 5];

    const float k1 = dtf / C1;
    const float k2 = dtf / C2;
    const float k3 = dtf / C3;

    // Coefficients pre-scaled by 1e-5 (y = dT * 1e-5). ulp-level change,
    // validated in R5 (passed, absmax 1024.0 vs threshold 3891).
    const float S    = 1.0e-5f;
    const float a11s = (k1 / R1) * S;
    const float a12s = (k1 / R2) * S;
    const float k1s  = k1 * S;
    const float a22s = (k2 / R2) * S;
    const float k2s  = k2 * S;
    const float a31s = (k3 / R1) * S;
    const float a33s = (k3 / R3) * S;

    const float TAME = 100000.0f;

    float Tin  = state0[b * 3 + 0];
    float Th   = state0[b * 3 + 1];
    float Tenv = state0[b * 3 + 2];

    float* op = out + (size_t)b * 3;
    const size_t ostride = (size_t)B * 3;

    for (int c = 0; c < T; c += CHUNK) {
        const int n = (T - c < CHUNK) ? (T - c) : CHUNK;

        __syncthreads();   // previous chunk's LDS reads done before overwrite
        for (int i = threadIdx.x; i < n * 3; i += 64)
            sext[i] = ext[(size_t)c * 3 + i];
        __syncthreads();

        // Software-pipelined ext triple: current step's values already in
        // registers; next step's ds_reads issue before the dependent chain.
        float Tout = sext[0];
        float hp   = sext[1];
        float sg   = sext[2];

#pragma unroll 6
        for (int t = 0; t < n; ++t) {
            // prefetch t+1 (overreads 3 floats past n*3 on last iter: padded)
            const float ToutN = sext[t * 3 + 3];
            const float hpN   = sext[t * 3 + 4];
            const float sgN   = sext[t * 3 + 5];

            // off-chain products (ext values were available last iteration)
            const float k1sg = k1s * sg;
            const float k2hp = k2s * hp;
            const float c3t  = a33s * Tout;

            const float u = Tin - Tenv;
            const float v = Tin - Th;

            const float y1 = fmaf(-a12s, v, fmaf(-a11s, u, k1sg));
            const float y2 = fmaf( a22s, v, k2hp);
            const float y3 = fmaf( a31s, u, fmaf(-a33s, Tenv, c3t));

            const float r1 = __builtin_amdgcn_rsqf(fmaf(y1, y1, 1.0f));
            const float r2 = __builtin_amdgcn_rsqf(fmaf(y2, y2, 1.0f));
            const float r3 = __builtin_amdgcn_rsqf(fmaf(y3, y3, 1.0f));

            Tin  = fmaf(y1 * TAME, r1, Tin);
            Th   = fmaf(y2 * TAME, r2, Th);
            Tenv = fmaf(y3 * TAME, r3, Tenv);

            op[0] = Tin;
            op[1] = Th;
            op[2] = Tenv;
            op += ostride;

            Tout = ToutN; hp = hpN; sg = sgN;
        }
    }
}

extern "C" void kernel_launch(void* const* d_in, const int* in_sizes, int n_in,
                              void* d_out, int out_size, void* d_ws, size_t ws_size,
                              hipStream_t stream) {
    const float* state0 = (const float*)d_in[0];
    const float* params = (const float*)d_in[1];
    const float* ext    = (const float*)d_in[2];
    const int*   dtp    = (const int*)d_in[3];
    float*       out    = (float*)d_out;

    const int B = in_sizes[0] / 3;   // 4096
    const int T = in_sizes[2] / 3;   // 8760

    const int block = 64;
    const int grid  = B / block;     // 64 blocks, one wave each
    tithte_kernel<<<grid, block, 0, stream>>>(state0, params, ext, dtp, out, B, T);
}